// Round 5
// baseline (457.770 us; speedup 1.0000x reference)
//
#include <hip/hip_runtime.h>
#include <hip/hip_bf16.h>

#define B_  8
#define C_  512
#define NN  16384
#define SPL 8
#define KB_ (NN / SPL)   // 2048 per gram block
#define TT  (KB_ / 64)   // 32 K-tiles of 64

typedef _Float16 half8 __attribute__((ext_vector_type(8)));
typedef float    f32x4 __attribute__((ext_vector_type(4)));

__device__ __forceinline__ unsigned short f2h(float x) {
    union { _Float16 h; unsigned short u; } cv;
    cv.h = (_Float16)x;
    return cv.u;
}

__device__ __forceinline__ void gload16(const unsigned short* src, unsigned short* ldst) {
    __builtin_amdgcn_global_load_lds(
        (const __attribute__((address_space(1))) void*)src,
        (__attribute__((address_space(3))) void*)ldst,
        16, 0, 0);
}

__global__ void ws_probe_kernel(float* out, float v) { out[0] = v; }

// ---------- kernel 1: pack fp32 [b][n][c] -> f16 transposed [b][c][n] ----------
__global__ __launch_bounds__(256) void pack_kernel(const float* __restrict__ in,
                                                   unsigned short* __restrict__ qT) {
    __shared__ unsigned short lh[64][72];
    int t  = threadIdx.x;
    int n0 = blockIdx.x * 64;
    int c0 = blockIdx.y * 64;
    int b  = blockIdx.z;
    const float* ib = in + ((size_t)b * NN + n0) * C_ + c0;
#pragma unroll
    for (int p = 0; p < 4; ++p) {
        int nl = p * 16 + (t >> 4);
        int cl = (t & 15) * 4;
        float4 v = *(const float4*)(ib + (size_t)nl * C_ + cl);
        lh[cl + 0][nl] = f2h(v.x);
        lh[cl + 1][nl] = f2h(v.y);
        lh[cl + 2][nl] = f2h(v.z);
        lh[cl + 3][nl] = f2h(v.w);
    }
    __syncthreads();
    size_t obase = ((size_t)b * C_ + c0) * NN + n0;
#pragma unroll
    for (int p = 0; p < 2; ++p) {
        int cr = p * 32 + (t >> 3);
        int nf = (t & 7) * 8;
        *(uint4*)(qT + obase + (size_t)cr * NN + nf) = *(const uint4*)&lh[cr][nf];
    }
}

// ---------- kernel 2: Gram partials, 256x256 tile, BK=64, pipelined ----------
// grid 256: b = bid&7 (XCD locality), r=bid>>3: tile=r&3 (tc,td), split=r>>2
// P layout: [split(8)][b][512][512] fp32
__global__ __launch_bounds__(512, 2) void gram_kernel(const unsigned short* __restrict__ qT,
                                                      float* __restrict__ P) {
    // A,B tiles: [256 rows][64 f16] = 32KB each, double-buffered, st_16x32 swizzle
    __shared__ unsigned short sA[2][16384];
    __shared__ unsigned short sB[2][16384];
    int t = threadIdx.x, lane = t & 63, wave = t >> 6;
    int wr = wave >> 2, wc = wave & 3;           // 2 x 4 wave grid
    int bid = blockIdx.x;
    int b = bid & 7, r = bid >> 3;
    int tile = r & 3, split = r >> 2;
    int tc = tile >> 1, td = tile & 1;
    size_t qb = (size_t)b * C_ * NN;
    const unsigned short* Ap = qT + qb + (size_t)(tc * 256) * NN + (size_t)split * KB_;
    const unsigned short* Bp = qT + qb + (size_t)(td * 256) * NN + (size_t)split * KB_;

    f32x4 acc[8][4];
#pragma unroll
    for (int m = 0; m < 8; ++m)
#pragma unroll
        for (int n = 0; n < 4; ++n) acc[m][n] = (f32x4){0.f, 0.f, 0.f, 0.f};

    // staging: per half (128 rows x 64 f16 = 16KB = 1024 x 16B chunks), 2 chunks/thread.
    // dest is LINEAR (c*16); source pre-swizzled: u = o ^ (((o>>9)&1)<<5)
    int o0 = t * 16,         u0 = o0 ^ (((o0 >> 9) & 1) << 5);
    int o1 = (t + 512) * 16, u1 = o1 ^ (((o1 >> 9) & 1) << 5);
    int rih0 = u0 >> 7, k0 = (u0 & 127) >> 1;
    int rih1 = u1 >> 7, k1 = (u1 & 127) >> 1;

#define STAGE(dst, dd, h, panel, kt)                                                        \
    do {                                                                                    \
        gload16((panel) + (size_t)((h)*128 + rih0) * NN + (kt)*64 + k0,                     \
                &dst[dd][(h)*8192 + t * 8]);                                                \
        gload16((panel) + (size_t)((h)*128 + rih1) * NN + (kt)*64 + k1,                     \
                &dst[dd][(h)*8192 + (t + 512) * 8]);                                        \
    } while (0)

    int g16 = (lane >> 4) * 16;  // k-slot byte offset within 128B row
#define AFRAG(dd, row, ks) \
    (*(const half8*)((const char*)&sA[dd][0] + (((row)*128 + (ks)*64 + g16) ^ (((row)&4) << 3))))
#define BFRAG(dd, row, ks) \
    (*(const half8*)((const char*)&sB[dd][0] + (((row)*128 + (ks)*64 + g16) ^ (((row)&4) << 3))))

    // prologue: stage tile 0 (order A0,B0,B1,A1), need first 3 halves -> vmcnt(2)
    STAGE(sA, 0, 0, Ap, 0);
    STAGE(sB, 0, 0, Bp, 0);
    STAGE(sB, 0, 1, Bp, 0);
    STAGE(sA, 0, 1, Ap, 0);
    asm volatile("s_waitcnt vmcnt(2)" ::: "memory");
    __builtin_amdgcn_s_barrier();

    for (int kt = 0; kt < TT; ++kt) {
        int d = kt & 1, nd = d ^ 1;
        // ---- region 1: quads (A-half0 x B-half0) and (A-half0 x B-half1) ----
        half8 aF[4][2], b0F[2][2], b1F[2][2];
#pragma unroll
        for (int m = 0; m < 4; ++m) {
            int row = wr * 64 + m * 16 + (lane & 15);
#pragma unroll
            for (int ks = 0; ks < 2; ++ks) aF[m][ks] = AFRAG(d, row, ks);
        }
#pragma unroll
        for (int n = 0; n < 2; ++n) {
            int row0 = wc * 32 + n * 16 + (lane & 15);
#pragma unroll
            for (int ks = 0; ks < 2; ++ks) {
                b0F[n][ks] = BFRAG(d, row0, ks);
                b1F[n][ks] = BFRAG(d, (row0 + 128), ks);
            }
        }
        if (kt + 1 < TT) {
            STAGE(sA, nd, 0, Ap, kt + 1);
            STAGE(sB, nd, 0, Bp, kt + 1);
            STAGE(sB, nd, 1, Bp, kt + 1);
        }
        __builtin_amdgcn_s_setprio(1);
#pragma unroll
        for (int m = 0; m < 4; ++m)
#pragma unroll
            for (int n = 0; n < 2; ++n)
#pragma unroll
                for (int ks = 0; ks < 2; ++ks) {
                    acc[m][n]     = __builtin_amdgcn_mfma_f32_16x16x32_f16(aF[m][ks], b0F[n][ks], acc[m][n],     0, 0, 0);
                    acc[m][n + 2] = __builtin_amdgcn_mfma_f32_16x16x32_f16(aF[m][ks], b1F[n][ks], acc[m][n + 2], 0, 0, 0);
                }
        __builtin_amdgcn_s_setprio(0);
        if (kt + 1 < TT) {
            asm volatile("s_waitcnt vmcnt(6)" ::: "memory");   // A-half1 of THIS tile landed
        } else {
            asm volatile("s_waitcnt vmcnt(0)" ::: "memory");   // last tile: no trailing stages
        }
        __builtin_amdgcn_s_barrier();
        // ---- region 2: quads (A-half1 x B-half1) and (A-half1 x B-half0), B frags cached ----
#pragma unroll
        for (int m = 0; m < 4; ++m) {
            int row = 128 + wr * 64 + m * 16 + (lane & 15);
#pragma unroll
            for (int ks = 0; ks < 2; ++ks) aF[m][ks] = AFRAG(d, row, ks);
        }
        if (kt + 1 < TT) STAGE(sA, nd, 1, Ap, kt + 1);
        __builtin_amdgcn_s_setprio(1);
#pragma unroll
        for (int m = 0; m < 4; ++m)
#pragma unroll
            for (int n = 0; n < 2; ++n)
#pragma unroll
                for (int ks = 0; ks < 2; ++ks) {
                    acc[m + 4][n + 2] = __builtin_amdgcn_mfma_f32_16x16x32_f16(aF[m][ks], b1F[n][ks], acc[m + 4][n + 2], 0, 0, 0);
                    acc[m + 4][n]     = __builtin_amdgcn_mfma_f32_16x16x32_f16(aF[m][ks], b0F[n][ks], acc[m + 4][n],     0, 0, 0);
                }
        __builtin_amdgcn_s_setprio(0);
        asm volatile("s_waitcnt vmcnt(2)" ::: "memory");       // next tile's A0,B0,B1 landed
        __builtin_amdgcn_s_barrier();
    }

    float* out = P + ((size_t)(split * 8 + b)) * (C_ * C_);
#pragma unroll
    for (int m = 0; m < 8; ++m) {
        int row0 = tc * 256 + wr * 64 + (m & 3) * 16 + (m >> 2) * 128 + (lane >> 4) * 4;
#pragma unroll
        for (int n = 0; n < 4; ++n) {
            int col = td * 256 + wc * 32 + (n & 1) * 16 + (n >> 1) * 128 + (lane & 15);
#pragma unroll
            for (int j = 0; j < 4; ++j)
                out[(size_t)(row0 + j) * C_ + col] = acc[m][n][j];
        }
    }
#undef STAGE
#undef AFRAG
#undef BFRAG
}

// ---------- kernel 3: sum splits + reversed softmax -> W^T f16 [b][d][c] ----------
// G symmetric (single flavor), softmax(max-G) == softmax(-G): w = exp(minG - G)/sum
__global__ __launch_bounds__(256) void softmax_kernel(const float* __restrict__ P,
                                                      unsigned short* __restrict__ WT) {
    __shared__ unsigned short lw[C_ * 4];
    int t = threadIdx.x, lane = t & 63, wave = t >> 6;
    int b = blockIdx.y;
    int c = blockIdx.x * 4 + wave;
    const float* base = P + (size_t)b * (C_ * C_) + (size_t)c * C_;

    float g[8];
    float mn = 3.4e38f;
#pragma unroll
    for (int k = 0; k < 8; ++k) {
        int d = k * 64 + lane;
        float v = 0.f;
#pragma unroll
        for (int s = 0; s < 8; ++s) v += base[(size_t)s * (8 * C_ * C_) + d];
        g[k] = v;
        mn = fminf(mn, v);
    }
#pragma unroll
    for (int o = 32; o; o >>= 1) mn = fminf(mn, __shfl_xor(mn, o));
    float w[8];
    float sum = 0.f;
#pragma unroll
    for (int k = 0; k < 8; ++k) { w[k] = __expf(mn - g[k]); sum += w[k]; }
#pragma unroll
    for (int o = 32; o; o >>= 1) sum += __shfl_xor(sum, o);
    float inv = 1.0f / sum;
#pragma unroll
    for (int k = 0; k < 8; ++k) {
        int d = k * 64 + lane;
        lw[d * 4 + wave] = f2h(w[k] * inv);
    }
    __syncthreads();
    int c0 = blockIdx.x * 4;
    for (int d = t; d < C_; d += 256)
        *(ushort4*)(WT + ((size_t)b * C_ + d) * C_ + c0) = *(ushort4*)&lw[d * 4];
}

// ---------- kernel 4: value = q @ W, out = gamma*value + in ----------
// Tile 64n x 512d per 512-thread block. A staged ONCE in LDS (64KB f16, swizzled);
// B (WT, L2-resident via b=bid&7) read directly global->regs. NO barriers in k-loop.
// Epilogue reads `in` back from the LDS A copy (f16) -> no global re-read.
__global__ __launch_bounds__(512, 4) void value_kernel(const float* __restrict__ in,
                                                       const unsigned short* __restrict__ WT,
                                                       const float* __restrict__ gamma,
                                                       float* __restrict__ out) {
    __shared__ unsigned short vA[64 * 512];      // [64 rows][512 c] f16, XOR-swizzled
    int t = threadIdx.x, lane = t & 63, wave = t >> 6;
    int wr = wave >> 2, wc = wave & 3;           // 2(n) x 4(d) waves
    int bid = blockIdx.x;
    int b = bid & 7, nt = bid >> 3;
    const float* Ain = in + ((size_t)b * NN + (size_t)nt * 64) * C_;
    const unsigned short* Bin = WT + (size_t)b * C_ * C_;

    // ---- stage A once: 64 rows x 512 fp32 -> f16 LDS. 4096 16B-chunks, 8/thread ----
#pragma unroll
    for (int i = 0; i < 8; ++i) {
        int chunk = i * 512 + t;
        int rr = chunk >> 6, c8 = (chunk & 63) * 8;
        const float* s = Ain + (size_t)rr * C_ + c8;
        float4 v0 = *(const float4*)s;
        float4 v1 = *(const float4*)(s + 4);
        half8 h;
        h[0] = (_Float16)v0.x; h[1] = (_Float16)v0.y; h[2] = (_Float16)v0.z; h[3] = (_Float16)v0.w;
        h[4] = (_Float16)v1.x; h[5] = (_Float16)v1.y; h[6] = (_Float16)v1.z; h[7] = (_Float16)v1.w;
        *(half8*)((char*)vA + ((rr * 1024 + c8 * 2) ^ ((rr & 7) << 4))) = h;
    }
    __syncthreads();

    f32x4 acc[2][8];
#pragma unroll
    for (int m = 0; m < 2; ++m)
#pragma unroll
        for (int n = 0; n < 8; ++n) acc[m][n] = (f32x4){0.f, 0.f, 0.f, 0.f};

    int g16 = (lane >> 4) * 16;                  // k-slot byte offset
    int l15 = lane & 15;
    // per-lane B base: row = wc*128 + l15, k-slot (lane>>4)*8 elems
    const unsigned short* Blane = Bin + (size_t)(wc * 128 + l15) * C_ + (lane >> 4) * 8;
    // per-lane A base rows for m=0,1
    int ar0 = wr * 32 + l15, ar1 = wr * 32 + 16 + l15;

    // ---- k-loop: no barriers; waves independent; B from global (L2), A from LDS ----
    for (int kt = 0; kt < 16; ++kt) {
        half8 aF0 = *(const half8*)((const char*)vA + ((ar0 * 1024 + kt * 64 + g16) ^ ((ar0 & 7) << 4)));
        half8 aF1 = *(const half8*)((const char*)vA + ((ar1 * 1024 + kt * 64 + g16) ^ ((ar1 & 7) << 4)));
        half8 bF[4];
#pragma unroll
        for (int n = 0; n < 4; ++n)
            bF[n] = *(const half8*)(Blane + (size_t)n * 16 * C_ + kt * 32);
#pragma unroll
        for (int n = 0; n < 4; ++n) {
            acc[0][n] = __builtin_amdgcn_mfma_f32_16x16x32_f16(aF0, bF[n], acc[0][n], 0, 0, 0);
            acc[1][n] = __builtin_amdgcn_mfma_f32_16x16x32_f16(aF1, bF[n], acc[1][n], 0, 0, 0);
        }
#pragma unroll
        for (int n = 0; n < 4; ++n)
            bF[n] = *(const half8*)(Blane + (size_t)(n + 4) * 16 * C_ + kt * 32);
#pragma unroll
        for (int n = 0; n < 4; ++n) {
            acc[0][n + 4] = __builtin_amdgcn_mfma_f32_16x16x32_f16(aF0, bF[n], acc[0][n + 4], 0, 0, 0);
            acc[1][n + 4] = __builtin_amdgcn_mfma_f32_16x16x32_f16(aF1, bF[n], acc[1][n + 4], 0, 0, 0);
        }
    }

    // ---- epilogue: out = gamma*acc + in (in read back from LDS f16 copy) ----
    float gm = gamma[0];
#pragma unroll
    for (int m = 0; m < 2; ++m) {
        int lr0 = wr * 32 + m * 16 + (lane >> 4) * 4;   // local row in 64-row tile
#pragma unroll
        for (int n = 0; n < 8; ++n) {
            int dd = wc * 128 + n * 16 + l15;
#pragma unroll
            for (int j = 0; j < 4; ++j) {
                int lr = lr0 + j;
                float iv = (float)(*(const _Float16*)((const char*)vA +
                                ((lr * 1024 + dd * 2) ^ ((lr & 7) << 4))));
                out[((size_t)b * NN + (size_t)nt * 64 + lr) * C_ + dd] = gm * acc[m][n][j] + iv;
            }
        }
    }
}

// ---------- launch ----------
extern "C" void kernel_launch(void* const* d_in, const int* in_sizes, int n_in,
                              void* d_out, int out_size, void* d_ws, size_t ws_size,
                              hipStream_t stream) {
    const float* in    = (const float*)d_in[0];
    const float* gamma = (const float*)d_in[1];
    float* out = (float*)d_out;

    const size_t q_elems = (size_t)B_ * C_ * NN;                 // 67.1M
    const size_t need = q_elems * 2                              // qT f16
                      + (size_t)SPL * B_ * C_ * C_ * 4           // P partials fp32
                      + (size_t)B_ * C_ * C_ * 2;                // W^T f16
    if (ws_size < need) {   // reveal ws_size via absmax if ever too small
        ws_probe_kernel<<<1, 1, 0, stream>>>(out, (float)ws_size);
        return;
    }

    unsigned short* qT = (unsigned short*)d_ws;
    float* P = (float*)(qT + q_elems);
    unsigned short* WT = (unsigned short*)(P + (size_t)SPL * B_ * C_ * C_);

    pack_kernel<<<dim3(NN / 64, C_ / 64, B_), 256, 0, stream>>>(in, qT);
    gram_kernel<<<256, 512, 0, stream>>>(qT, P);
    softmax_kernel<<<dim3(C_ / 4, B_), 256, 0, stream>>>(P, WT);
    value_kernel<<<2048, 512, 0, stream>>>(in, WT, gamma, out);
}

// Round 6
// 347.703 us; speedup vs baseline: 1.3166x; 1.3166x over previous
//
#include <hip/hip_runtime.h>
#include <hip/hip_bf16.h>

#define B_  8
#define C_  512
#define NN  16384
#define SPL 8
#define KB_ (NN / SPL)   // 2048 per gram block
#define TT  (KB_ / 64)   // 32 K-tiles of 64

typedef _Float16 half8 __attribute__((ext_vector_type(8)));
typedef _Float16 half4 __attribute__((ext_vector_type(4)));
typedef float    f32x4 __attribute__((ext_vector_type(4)));

__device__ __forceinline__ unsigned short f2h(float x) {
    union { _Float16 h; unsigned short u; } cv;
    cv.h = (_Float16)x;
    return cv.u;
}

__device__ __forceinline__ void gload16(const unsigned short* src, unsigned short* ldst) {
    __builtin_amdgcn_global_load_lds(
        (const __attribute__((address_space(1))) void*)src,
        (__attribute__((address_space(3))) void*)ldst,
        16, 0, 0);
}

__global__ void ws_probe_kernel(float* out, float v) { out[0] = v; }

// ---------- kernel 1: pack fp32 [b][n][c] -> f16 transposed [b][c][n] ----------
__global__ __launch_bounds__(256) void pack_kernel(const float* __restrict__ in,
                                                   unsigned short* __restrict__ qT) {
    __shared__ unsigned short lh[64][72];
    int t  = threadIdx.x;
    int n0 = blockIdx.x * 64;
    int c0 = blockIdx.y * 64;
    int b  = blockIdx.z;
    const float* ib = in + ((size_t)b * NN + n0) * C_ + c0;
#pragma unroll
    for (int p = 0; p < 4; ++p) {
        int nl = p * 16 + (t >> 4);
        int cl = (t & 15) * 4;
        float4 v = *(const float4*)(ib + (size_t)nl * C_ + cl);
        lh[cl + 0][nl] = f2h(v.x);
        lh[cl + 1][nl] = f2h(v.y);
        lh[cl + 2][nl] = f2h(v.z);
        lh[cl + 3][nl] = f2h(v.w);
    }
    __syncthreads();
    size_t obase = ((size_t)b * C_ + c0) * NN + n0;
#pragma unroll
    for (int p = 0; p < 2; ++p) {
        int cr = p * 32 + (t >> 3);
        int nf = (t & 7) * 8;
        *(uint4*)(qT + obase + (size_t)cr * NN + nf) = *(const uint4*)&lh[cr][nf];
    }
}

// ---------- kernel 2: Gram partials, 256x256 tile, BK=64, pipelined ----------
// grid 256: b = bid&7 (XCD locality), r=bid>>3: tile=r&3 (tc,td), split=r>>2
// P layout: [split(8)][b][512][512] fp32
__global__ __launch_bounds__(512, 2) void gram_kernel(const unsigned short* __restrict__ qT,
                                                      float* __restrict__ P) {
    // A,B tiles: [256 rows][64 f16] = 32KB each, double-buffered, st_16x32 swizzle
    __shared__ unsigned short sA[2][16384];
    __shared__ unsigned short sB[2][16384];
    int t = threadIdx.x, lane = t & 63, wave = t >> 6;
    int wr = wave >> 2, wc = wave & 3;           // 2 x 4 wave grid
    int bid = blockIdx.x;
    int b = bid & 7, r = bid >> 3;
    int tile = r & 3, split = r >> 2;
    int tc = tile >> 1, td = tile & 1;
    size_t qb = (size_t)b * C_ * NN;
    const unsigned short* Ap = qT + qb + (size_t)(tc * 256) * NN + (size_t)split * KB_;
    const unsigned short* Bp = qT + qb + (size_t)(td * 256) * NN + (size_t)split * KB_;

    f32x4 acc[8][4];
#pragma unroll
    for (int m = 0; m < 8; ++m)
#pragma unroll
        for (int n = 0; n < 4; ++n) acc[m][n] = (f32x4){0.f, 0.f, 0.f, 0.f};

    // staging: per half (128 rows x 64 f16 = 16KB = 1024 x 16B chunks), 2 chunks/thread.
    // dest is LINEAR (c*16); source pre-swizzled: u = o ^ (((o>>9)&1)<<5)
    int o0 = t * 16,         u0 = o0 ^ (((o0 >> 9) & 1) << 5);
    int o1 = (t + 512) * 16, u1 = o1 ^ (((o1 >> 9) & 1) << 5);
    int rih0 = u0 >> 7, k0 = (u0 & 127) >> 1;
    int rih1 = u1 >> 7, k1 = (u1 & 127) >> 1;

#define STAGE(dst, dd, h, panel, kt)                                                        \
    do {                                                                                    \
        gload16((panel) + (size_t)((h)*128 + rih0) * NN + (kt)*64 + k0,                     \
                &dst[dd][(h)*8192 + t * 8]);                                                \
        gload16((panel) + (size_t)((h)*128 + rih1) * NN + (kt)*64 + k1,                     \
                &dst[dd][(h)*8192 + (t + 512) * 8]);                                        \
    } while (0)

    int g16 = (lane >> 4) * 16;  // k-slot byte offset within 128B row
#define AFRAG(dd, row, ks) \
    (*(const half8*)((const char*)&sA[dd][0] + (((row)*128 + (ks)*64 + g16) ^ (((row)&4) << 3))))
#define BFRAG(dd, row, ks) \
    (*(const half8*)((const char*)&sB[dd][0] + (((row)*128 + (ks)*64 + g16) ^ (((row)&4) << 3))))

    // prologue: stage tile 0 (order A0,B0,B1,A1), need first 3 halves -> vmcnt(2)
    STAGE(sA, 0, 0, Ap, 0);
    STAGE(sB, 0, 0, Bp, 0);
    STAGE(sB, 0, 1, Bp, 0);
    STAGE(sA, 0, 1, Ap, 0);
    asm volatile("s_waitcnt vmcnt(2)" ::: "memory");
    __builtin_amdgcn_s_barrier();

    for (int kt = 0; kt < TT; ++kt) {
        int d = kt & 1, nd = d ^ 1;
        // ---- region 1: quads (A-half0 x B-half0) and (A-half0 x B-half1) ----
        half8 aF[4][2], b0F[2][2], b1F[2][2];
#pragma unroll
        for (int m = 0; m < 4; ++m) {
            int row = wr * 64 + m * 16 + (lane & 15);
#pragma unroll
            for (int ks = 0; ks < 2; ++ks) aF[m][ks] = AFRAG(d, row, ks);
        }
#pragma unroll
        for (int n = 0; n < 2; ++n) {
            int row0 = wc * 32 + n * 16 + (lane & 15);
#pragma unroll
            for (int ks = 0; ks < 2; ++ks) {
                b0F[n][ks] = BFRAG(d, row0, ks);
                b1F[n][ks] = BFRAG(d, (row0 + 128), ks);
            }
        }
        if (kt + 1 < TT) {
            STAGE(sA, nd, 0, Ap, kt + 1);
            STAGE(sB, nd, 0, Bp, kt + 1);
            STAGE(sB, nd, 1, Bp, kt + 1);
        }
        __builtin_amdgcn_s_setprio(1);
#pragma unroll
        for (int m = 0; m < 4; ++m)
#pragma unroll
            for (int n = 0; n < 2; ++n)
#pragma unroll
                for (int ks = 0; ks < 2; ++ks) {
                    acc[m][n]     = __builtin_amdgcn_mfma_f32_16x16x32_f16(aF[m][ks], b0F[n][ks], acc[m][n],     0, 0, 0);
                    acc[m][n + 2] = __builtin_amdgcn_mfma_f32_16x16x32_f16(aF[m][ks], b1F[n][ks], acc[m][n + 2], 0, 0, 0);
                }
        __builtin_amdgcn_s_setprio(0);
        if (kt + 1 < TT) {
            asm volatile("s_waitcnt vmcnt(6)" ::: "memory");   // A-half1 of THIS tile landed
        } else {
            asm volatile("s_waitcnt vmcnt(0)" ::: "memory");   // last tile: no trailing stages
        }
        __builtin_amdgcn_s_barrier();
        // ---- region 2: quads (A-half1 x B-half1) and (A-half1 x B-half0), B frags cached ----
#pragma unroll
        for (int m = 0; m < 4; ++m) {
            int row = 128 + wr * 64 + m * 16 + (lane & 15);
#pragma unroll
            for (int ks = 0; ks < 2; ++ks) aF[m][ks] = AFRAG(d, row, ks);
        }
        if (kt + 1 < TT) STAGE(sA, nd, 1, Ap, kt + 1);
        __builtin_amdgcn_s_setprio(1);
#pragma unroll
        for (int m = 0; m < 4; ++m)
#pragma unroll
            for (int n = 0; n < 2; ++n)
#pragma unroll
                for (int ks = 0; ks < 2; ++ks) {
                    acc[m + 4][n + 2] = __builtin_amdgcn_mfma_f32_16x16x32_f16(aF[m][ks], b1F[n][ks], acc[m + 4][n + 2], 0, 0, 0);
                    acc[m + 4][n]     = __builtin_amdgcn_mfma_f32_16x16x32_f16(aF[m][ks], b0F[n][ks], acc[m + 4][n],     0, 0, 0);
                }
        __builtin_amdgcn_s_setprio(0);
        asm volatile("s_waitcnt vmcnt(2)" ::: "memory");       // next tile's A0,B0,B1 landed
        __builtin_amdgcn_s_barrier();
    }

    float* out = P + ((size_t)(split * 8 + b)) * (C_ * C_);
#pragma unroll
    for (int m = 0; m < 8; ++m) {
        int row0 = tc * 256 + wr * 64 + (m & 3) * 16 + (m >> 2) * 128 + (lane >> 4) * 4;
#pragma unroll
        for (int n = 0; n < 4; ++n) {
            int col = td * 256 + wc * 32 + (n & 1) * 16 + (n >> 1) * 128 + (lane & 15);
#pragma unroll
            for (int j = 0; j < 4; ++j)
                out[(size_t)(row0 + j) * C_ + col] = acc[m][n][j];
        }
    }
#undef STAGE
#undef AFRAG
#undef BFRAG
}

// ---------- kernel 3: sum splits + reversed softmax -> W^T f16 [b][d][c] ----------
// G symmetric (single flavor), softmax(max-G) == softmax(-G): w = exp(minG - G)/sum
__global__ __launch_bounds__(256) void softmax_kernel(const float* __restrict__ P,
                                                      unsigned short* __restrict__ WT) {
    __shared__ unsigned short lw[C_ * 4];
    int t = threadIdx.x, lane = t & 63, wave = t >> 6;
    int b = blockIdx.y;
    int c = blockIdx.x * 4 + wave;
    const float* base = P + (size_t)b * (C_ * C_) + (size_t)c * C_;

    float g[8];
    float mn = 3.4e38f;
#pragma unroll
    for (int k = 0; k < 8; ++k) {
        int d = k * 64 + lane;
        float v = 0.f;
#pragma unroll
        for (int s = 0; s < 8; ++s) v += base[(size_t)s * (8 * C_ * C_) + d];
        g[k] = v;
        mn = fminf(mn, v);
    }
#pragma unroll
    for (int o = 32; o; o >>= 1) mn = fminf(mn, __shfl_xor(mn, o));
    float w[8];
    float sum = 0.f;
#pragma unroll
    for (int k = 0; k < 8; ++k) { w[k] = __expf(mn - g[k]); sum += w[k]; }
#pragma unroll
    for (int o = 32; o; o >>= 1) sum += __shfl_xor(sum, o);
    float inv = 1.0f / sum;
#pragma unroll
    for (int k = 0; k < 8; ++k) {
        int d = k * 64 + lane;
        lw[d * 4 + wave] = f2h(w[k] * inv);
    }
    __syncthreads();
    int c0 = blockIdx.x * 4;
    for (int d = t; d < C_; d += 256)
        *(ushort4*)(WT + ((size_t)b * C_ + d) * C_ + c0) = *(ushort4*)&lw[d * 4];
}

// ---------- kernel 4: value = q @ W, out = gamma*value + in ----------
// 1024 threads, tile 128n x 512d, BK=32, 16 waves (4n x 4d), wave tile 32x128,
// acc[2][8]=64 regs. B LDS-dbuf via gload_lds (swizzled source); A reg-staged
// fp32->f16 ds_write dbuf. Raw barriers with placed waitcnt AFTER the MFMA
// section (loads get the whole compute phase to land; no per-step full drain
// before compute). 80KB LDS, 1 block = 16 waves/CU.
__global__ __launch_bounds__(1024) void value_kernel(const float* __restrict__ in,
                                                     const unsigned short* __restrict__ WT,
                                                     const float* __restrict__ gamma,
                                                     float* __restrict__ out) {
    __shared__ unsigned short sB[2][512 * 32];   // 32 KB each, XOR-swizzled
    __shared__ unsigned short sA[2][128 * 32];   // 8 KB each, XOR-swizzled
    int t = threadIdx.x, lane = t & 63;
    int wave = t >> 6;
    int wr = wave >> 2, wc = wave & 3;           // 4(n) x 4(d) waves
    int bid = blockIdx.x;
    int b = bid & 7, nt = bid >> 3;              // nt 0..127
    const float* Ain = in + ((size_t)b * NN + (size_t)nt * 128) * C_;
    const unsigned short* Bin = WT + (size_t)b * C_ * C_;

    f32x4 acc[2][8];
#pragma unroll
    for (int m = 0; m < 2; ++m)
#pragma unroll
        for (int n = 0; n < 8; ++n) acc[m][n] = (f32x4){0.f, 0.f, 0.f, 0.f};

    // B staging: 2048 16B chunks, 2/thread; linear dest, pre-swizzled source
    // (read swizzle: byte = (row*64+g16) ^ (((row>>1)&3)<<4); as fn of lin: bits 4-5 ^= (lin>>7)&3)
    int boff[2];
#pragma unroll
    for (int p = 0; p < 2; ++p) {
        int o = (t + p * 1024) * 16;
        int u = o ^ (((o >> 7) & 3) << 4);
        boff[p] = (u >> 6) * C_ + ((u & 63) >> 1);
    }
    // A staging: 1024 threads x 4 floats = 128 rows x 32 c; 8 threads/row
    int arow = t >> 3, acol = (t & 7) * 4;
    int aoff = arow * C_ + acol;
    int awr  = (arow * 64 + acol * 2) ^ ((arow & 7) << 4);

    auto stageB = [&](int nb, int kt) {
        gload16(Bin + (size_t)boff[0] + kt * 32, &sB[nb][t * 8]);
        gload16(Bin + (size_t)boff[1] + kt * 32, &sB[nb][(t + 1024) * 8]);
    };
    auto loadA = [&](int kt) -> float4 {
        return *(const float4*)(Ain + aoff + kt * 32);
    };
    auto writeA = [&](int nb, float4 v) {
        half4 h;
        h[0] = (_Float16)v.x; h[1] = (_Float16)v.y; h[2] = (_Float16)v.z; h[3] = (_Float16)v.w;
        *(half4*)((char*)&sA[nb][0] + awr) = h;
    };

    // prologue
    float4 a0 = loadA(0);
    stageB(0, 0);
    writeA(0, a0);
    asm volatile("s_waitcnt vmcnt(0) lgkmcnt(0)" ::: "memory");
    __builtin_amdgcn_s_barrier();

    int g16 = (lane >> 4) * 16;
    int l15 = lane & 15;
    for (int kt = 0; kt < 16; ++kt) {
        int cur = kt & 1, nd = cur ^ 1;
        float4 ar;
        if (kt < 15) {
            ar = loadA(kt + 1);      // 1 vm op (oldest)
            stageB(nd, kt + 1);      // 2 vm ops
        }
        const char* pa = (const char*)&sA[cur][0];
        const char* pb = (const char*)&sB[cur][0];
        half8 aF[2], bF[4];
#pragma unroll
        for (int m = 0; m < 2; ++m) {
            int row = wr * 32 + m * 16 + l15;
            aF[m] = *(const half8*)(pa + ((row * 64 + g16) ^ ((row & 7) << 4)));
        }
#pragma unroll
        for (int n = 0; n < 4; ++n) {
            int row = wc * 128 + n * 16 + l15;
            bF[n] = *(const half8*)(pb + ((row * 64 + g16) ^ (((row >> 1) & 3) << 4)));
        }
        __builtin_amdgcn_s_setprio(1);
#pragma unroll
        for (int n = 0; n < 4; ++n) {
            acc[0][n] = __builtin_amdgcn_mfma_f32_16x16x32_f16(aF[0], bF[n], acc[0][n], 0, 0, 0);
            acc[1][n] = __builtin_amdgcn_mfma_f32_16x16x32_f16(aF[1], bF[n], acc[1][n], 0, 0, 0);
        }
        __builtin_amdgcn_s_setprio(0);
#pragma unroll
        for (int n = 0; n < 4; ++n) {
            int row = wc * 128 + (n + 4) * 16 + l15;
            bF[n] = *(const half8*)(pb + ((row * 64 + g16) ^ (((row >> 1) & 3) << 4)));
        }
        __builtin_amdgcn_s_setprio(1);
#pragma unroll
        for (int n = 0; n < 4; ++n) {
            acc[0][n + 4] = __builtin_amdgcn_mfma_f32_16x16x32_f16(aF[0], bF[n], acc[0][n + 4], 0, 0, 0);
            acc[1][n + 4] = __builtin_amdgcn_mfma_f32_16x16x32_f16(aF[1], bF[n], acc[1][n + 4], 0, 0, 0);
        }
        __builtin_amdgcn_s_setprio(0);
        if (kt < 15) {
            asm volatile("s_waitcnt vmcnt(2)" ::: "memory");   // A(kt+1) landed (B's 2 may be in flight)
            writeA(nd, ar);
            asm volatile("s_waitcnt vmcnt(0) lgkmcnt(0)" ::: "memory");  // B(kt+1) + A ds_write done
        }
        __builtin_amdgcn_s_barrier();
    }

    // epilogue: out = gamma*acc + in (in via L3)
    float gm = gamma[0];
#pragma unroll
    for (int m = 0; m < 2; ++m) {
        int nrow0 = nt * 128 + wr * 32 + m * 16 + (lane >> 4) * 4;
#pragma unroll
        for (int n = 0; n < 8; ++n) {
            int dd = wc * 128 + n * 16 + l15;
#pragma unroll
            for (int j = 0; j < 4; ++j) {
                size_t idx = ((size_t)b * NN + (nrow0 + j)) * C_ + dd;
                out[idx] = gm * acc[m][n][j] + in[idx];
            }
        }
    }
}

// ---------- launch ----------
extern "C" void kernel_launch(void* const* d_in, const int* in_sizes, int n_in,
                              void* d_out, int out_size, void* d_ws, size_t ws_size,
                              hipStream_t stream) {
    const float* in    = (const float*)d_in[0];
    const float* gamma = (const float*)d_in[1];
    float* out = (float*)d_out;

    const size_t q_elems = (size_t)B_ * C_ * NN;                 // 67.1M
    const size_t need = q_elems * 2                              // qT f16
                      + (size_t)SPL * B_ * C_ * C_ * 4           // P partials fp32
                      + (size_t)B_ * C_ * C_ * 2;                // W^T f16
    if (ws_size < need) {   // reveal ws_size via absmax if ever too small
        ws_probe_kernel<<<1, 1, 0, stream>>>(out, (float)ws_size);
        return;
    }

    unsigned short* qT = (unsigned short*)d_ws;
    float* P = (float*)(qT + q_elems);
    unsigned short* WT = (unsigned short*)(P + (size_t)SPL * B_ * C_ * C_);

    pack_kernel<<<dim3(NN / 64, C_ / 64, B_), 256, 0, stream>>>(in, qT);
    gram_kernel<<<256, 512, 0, stream>>>(qT, P);
    softmax_kernel<<<dim3(C_ / 4, B_), 256, 0, stream>>>(P, WT);
    value_kernel<<<1024, 1024, 0, stream>>>(in, WT, gamma, out);
}